// Round 2
// baseline (180.306 us; speedup 1.0000x reference)
//
#include <hip/hip_runtime.h>

// B=2, T=2048, C=1024, H=16, DQK=DV=64. Inputs fp32, output fp32, bf16 MFMA inside.

typedef short bf16x4 __attribute__((ext_vector_type(4)));
typedef short bf16x8 __attribute__((ext_vector_type(8)));
typedef float f32x4 __attribute__((ext_vector_type(4)));

#define MFMA_BF16 __builtin_amdgcn_mfma_f32_16x16x32_bf16

// log2(e)/8: Q pre-scale so softmax runs in base-2 domain (exp2 = bare v_exp_f32)
#define QSCALE 0.18033688011112042f

__device__ __forceinline__ unsigned short f2bf(float f) {
    union { float f; unsigned u; } un; un.f = f;
    unsigned r = un.u + 0x7fffu + ((un.u >> 16) & 1u);  // RNE
    return (unsigned short)(r >> 16);
}
__device__ __forceinline__ unsigned pk2(float a, float b) {
    return (unsigned)f2bf(a) | ((unsigned)f2bf(b) << 16);
}
// truncating pack of two floats into packed bf16x2
__device__ __forceinline__ unsigned pk2t(float a, float b) {
    union { float f; unsigned u; } ua, ub; ua.f = a; ub.f = b;
    return (ua.u >> 16) | (ub.u & 0xffff0000u);
}
__device__ __forceinline__ void gload16(const void* g, void* l) {
    __builtin_amdgcn_global_load_lds(
        (const __attribute__((address_space(1))) unsigned int*)g,
        (__attribute__((address_space(3))) unsigned int*)l, 16, 0, 0);
}

// ---------- fused prep: x/wq/wk/wv fp32->bf16, wo fp32->bf16 transposed ----------
__global__ __launch_bounds__(256) void prep(
    const float* __restrict__ x, const float* __restrict__ wq,
    const float* __restrict__ wk, const float* __restrict__ wv,
    const float* __restrict__ wo,
    unsigned short* __restrict__ x16, unsigned short* __restrict__ wq16,
    unsigned short* __restrict__ wk16, unsigned short* __restrict__ wv16,
    unsigned short* __restrict__ wot)
{
    const int bid = blockIdx.x;
    if (bid < 3584) {
        const float* s; unsigned short* d; int off;
        if (bid < 2048)      { s = x;  d = x16;  off = bid * 2048; }
        else if (bid < 2560) { s = wq; d = wq16; off = (bid - 2048) * 2048; }
        else if (bid < 3072) { s = wk; d = wk16; off = (bid - 2560) * 2048; }
        else                 { s = wv; d = wv16; off = (bid - 3072) * 2048; }
        int i = off + threadIdx.x * 8;
        float4 f0 = *(const float4*)&s[i], f1 = *(const float4*)&s[i + 4];
        uint4 o;
        o.x = pk2(f0.x, f0.y); o.y = pk2(f0.z, f0.w);
        o.z = pk2(f1.x, f1.y); o.w = pk2(f1.z, f1.w);
        *(uint4*)&d[i] = o;
    } else {
        // wo [K=1024][N=1024] -> wot [N][K] bf16
        __shared__ unsigned short t[64 * 72];
        const int b2 = bid - 3584;
        const int k0 = (b2 & 15) << 6, n0 = (b2 >> 4) << 6;
        const int r = threadIdx.x >> 2, cg = (threadIdx.x & 3) << 4;
        const float* src = &wo[(k0 + r) * 1024 + n0 + cg];
        #pragma unroll
        for (int j = 0; j < 16; j += 4) {
            float4 f = *(const float4*)&src[j];
            t[(cg + j + 0) * 72 + r] = f2bf(f.x);
            t[(cg + j + 1) * 72 + r] = f2bf(f.y);
            t[(cg + j + 2) * 72 + r] = f2bf(f.z);
            t[(cg + j + 3) * 72 + r] = f2bf(f.w);
        }
        __syncthreads();
        unsigned short* dst = &wot[(n0 + r) * 1024 + k0 + cg];
        unsigned short* tr = &t[r * 72 + cg];
        unsigned v[16];
        #pragma unroll
        for (int j = 0; j < 16; ++j) v[j] = tr[j];
        uint4 o0, o1;
        o0.x = v[0] | (v[1] << 16);   o0.y = v[2] | (v[3] << 16);
        o0.z = v[4] | (v[5] << 16);   o0.w = v[6] | (v[7] << 16);
        o1.x = v[8] | (v[9] << 16);   o1.y = v[10] | (v[11] << 16);
        o1.z = v[12] | (v[13] << 16); o1.w = v[14] | (v[15] << 16);
        *(uint4*)&dst[0] = o0;
        *(uint4*)&dst[8] = o1;
    }
}

// ---------- 128x128 bf16 GEMM, K=1024: BK=32 dbuf gload16, fully unrolled ----------
// R16 data-side XOR bank swizzle (validated): G-chunk = (lane&3) ^ ((r16>>1)&3);
// readers use chunk l4 ^ ((l15>>1)&3). mode 2 = vtb store with sigma permutation.
__device__ __forceinline__ void gemm_body(
    const unsigned short* __restrict__ A, const unsigned short* __restrict__ Bm,
    void* __restrict__ C, int m0, int n0, int mode, int ldc, float sc)
{
    __shared__ unsigned short sa[2][128 * 32];
    __shared__ unsigned short sb[2][128 * 32];
    const int tid = threadIdx.x, wave = tid >> 6, lane = tid & 63;
    const int l15 = lane & 15, l4 = lane >> 4;
    const int wm = (wave >> 1) << 6, wn = (wave & 1) << 6;

    const int r16 = lane >> 2;                               // 0..15
    const int gcol = (((lane & 3) ^ ((r16 >> 1) & 3)) << 3); // swizzled 16B chunk
    const int rcol = (l4 ^ ((l15 >> 1) & 3)) << 3;           // read-side chunk
    const unsigned short* Ag0 = &A[(size_t)(m0 + wave * 16 + r16) * 1024 + gcol];
    const unsigned short* Ag1 = Ag0 + (size_t)64 * 1024;
    const unsigned short* Bg0 = &Bm[(size_t)(n0 + wave * 16 + r16) * 1024 + gcol];
    const unsigned short* Bg1 = Bg0 + (size_t)64 * 1024;
    const int lb0 = (wave * 16) * 32;      // wave-uniform LDS bases (elements)
    const int lb1 = (64 + wave * 16) * 32;

    gload16(Ag0, &sa[0][lb0]);
    gload16(Ag1, &sa[0][lb1]);
    gload16(Bg0, &sb[0][lb0]);
    gload16(Bg1, &sb[0][lb1]);
    __syncthreads();

    f32x4 acc[4][4] = {};

    #pragma unroll
    for (int kk = 0; kk < 32; ++kk) {
        const int cur = kk & 1;
        if (kk < 31) {
            const int off = (kk + 1) * 32;
            const int nxt = 1 - cur;
            gload16(Ag0 + off, &sa[nxt][lb0]);
            gload16(Ag1 + off, &sa[nxt][lb1]);
            gload16(Bg0 + off, &sb[nxt][lb0]);
            gload16(Bg1 + off, &sb[nxt][lb1]);
        }
        bf16x8 af[4], bf4[4];
        #pragma unroll
        for (int i = 0; i < 4; ++i)
            af[i] = *(const bf16x8*)&sa[cur][(wm + i * 16 + l15) * 32 + rcol];
        #pragma unroll
        for (int j = 0; j < 4; ++j)
            bf4[j] = *(const bf16x8*)&sb[cur][(wn + j * 16 + l15) * 32 + rcol];
        #pragma unroll
        for (int i = 0; i < 4; ++i)
            #pragma unroll
            for (int j = 0; j < 4; ++j)
                acc[i][j] = MFMA_BF16(af[i], bf4[j], acc[i][j], 0, 0, 0);
        __syncthreads();   // next-slab loads have flown during the MFMAs above
    }

    #pragma unroll
    for (int i = 0; i < 4; ++i)
        #pragma unroll
        for (int j = 0; j < 4; ++j)
            #pragma unroll
            for (int r = 0; r < 4; ++r) {
                int row = m0 + wm + i * 16 + l4 * 4 + r;
                int col = n0 + wn + j * 16 + l15;
                float val = acc[i][j][r];
                if (mode == 0) {
                    int nb = row >> 11, t = row & 2047;
                    int hh = col >> 6, dd = col & 63;
                    ((unsigned short*)C)[(((nb << 4) + hh) * 2048 + t) * 64 + dd] =
                        f2bf(val * sc);
                } else if (mode == 1) {
                    ((float*)C)[(size_t)row * ldc + col] = val;
                } else {
                    // sigma permutation within each 32-col block (see R15)
                    int s = col & 31;
                    int cp = (col & ~31) | (((s >> 2) & 3) << 3)
                                         | (((s >> 4) & 1) << 2) | (s & 3);
                    ((unsigned short*)C)[(size_t)row * ldc + cp] = f2bf(val);
                }
            }
}

// grid 768: [0,512) QK fused | [512,768) V^T = Wv @ X^T (sigma-permuted cols)
__global__ __launch_bounds__(256) void proj(
    const unsigned short* __restrict__ x16,
    const unsigned short* __restrict__ wq16,
    const unsigned short* __restrict__ wk16,
    const unsigned short* __restrict__ wv16,
    unsigned short* __restrict__ qbuf,
    unsigned short* __restrict__ kbuf,
    unsigned short* __restrict__ vtb)
{
    const int bid = blockIdx.x;
    if (bid < 512) {
        int m0 = (bid & 31) << 7;
        int n0g = (bid >> 5) << 7;
        if (n0g < 1024)
            gemm_body(x16, wq16, qbuf, m0, n0g, 0, 0, QSCALE);
        else
            gemm_body(x16, wk16, kbuf, m0, n0g - 1024, 0, 0, 1.0f);
    } else {
        int v = bid - 512;
        gemm_body(wv16, x16, vtb, (v & 7) << 7, (v >> 3) << 7, 2, 4096, 1.0f);
    }
}

// ---------- out = Y @ Wo^T: 128x64 tiles, grid 512 (2 blocks/CU) ----------
// R18: 128x128/grid-256 was exactly 1 block/CU -> the per-K-step barrier drain
// had no co-resident block to hide under (saved only ~1.4us vs 64^2). 128x64
// tiles give 512 blocks = 2/CU; same BK=32 dbuf gload16 skeleton + validated
// XOR swizzle; identical K-summation order -> bitwise-identical output.
// Waves 2M x 2N: wave w owns rows wm=(w>>1)*64, cols wn=(w&1)*32. acc[4][2].
__global__ __launch_bounds__(256) void outp(
    const unsigned short* __restrict__ ybuf,
    const unsigned short* __restrict__ wot,
    float* __restrict__ out)
{
    __shared__ unsigned short sa[2][128 * 32];
    __shared__ unsigned short sb[2][64 * 32];
    const int tid = threadIdx.x, wave = tid >> 6, lane = tid & 63;
    const int l15 = lane & 15, l4 = lane >> 4;
    const int bid = blockIdx.x;
    const int m0 = (bid & 31) << 7;       // 32 m-tiles over 4096 rows
    const int n0 = (bid >> 5) << 6;       // 16 n-tiles over 1024 cols
    const int wm = (wave >> 1) << 6, wn = (wave & 1) << 5;

    const int r16 = lane >> 2;
    const int gcol = (((lane & 3) ^ ((r16 >> 1) & 3)) << 3);
    const int rcol = (l4 ^ ((l15 >> 1) & 3)) << 3;
    const unsigned short* Ag0 = &ybuf[(size_t)(m0 + wave * 16 + r16) * 1024 + gcol];
    const unsigned short* Ag1 = Ag0 + (size_t)64 * 1024;
    const unsigned short* Bg0 = &wot[(size_t)(n0 + wave * 16 + r16) * 1024 + gcol];
    const int lba0 = (wave * 16) * 32, lba1 = (64 + wave * 16) * 32;
    const int lbb = (wave * 16) * 32;

    gload16(Ag0, &sa[0][lba0]);
    gload16(Ag1, &sa[0][lba1]);
    gload16(Bg0, &sb[0][lbb]);
    __syncthreads();

    f32x4 acc[4][2] = {};

    #pragma unroll
    for (int kk = 0; kk < 32; ++kk) {
        const int cur = kk & 1;
        if (kk < 31) {
            const int off = (kk + 1) * 32;
            const int nxt = 1 - cur;
            gload16(Ag0 + off, &sa[nxt][lba0]);
            gload16(Ag1 + off, &sa[nxt][lba1]);
            gload16(Bg0 + off, &sb[nxt][lbb]);
        }
        bf16x8 af[4], bf2[2];
        #pragma unroll
        for (int i = 0; i < 4; ++i)
            af[i] = *(const bf16x8*)&sa[cur][(wm + i * 16 + l15) * 32 + rcol];
        #pragma unroll
        for (int j = 0; j < 2; ++j)
            bf2[j] = *(const bf16x8*)&sb[cur][(wn + j * 16 + l15) * 32 + rcol];
        #pragma unroll
        for (int i = 0; i < 4; ++i)
            #pragma unroll
            for (int j = 0; j < 2; ++j)
                acc[i][j] = MFMA_BF16(af[i], bf2[j], acc[i][j], 0, 0, 0);
        __syncthreads();
    }

    #pragma unroll
    for (int i = 0; i < 4; ++i)
        #pragma unroll
        for (int j = 0; j < 2; ++j)
            #pragma unroll
            for (int r = 0; r < 4; ++r) {
                int row = m0 + wm + i * 16 + l4 * 4 + r;
                int col = n0 + wn + j * 16 + l15;
                out[(size_t)row * 1024 + col] = acc[i][j][r];
            }
}

// ---------- flash causal attention: S^T form, gload16-dbuf staging (R12 recipe) ----------
// K and V^T rows are 128B-contiguous in global, so global_load_lds stages them
// directly (no VGPR transit, no ds_write) into packed [row][64] tiles.
// Data-side XOR chunk swizzle: lane fetches global chunk (lane&7)^((lane>>3)&7),
// so LDS[r][c] = G[r][c^(r&7)]; readers use chunk (4ks+l4)^(l15&7) -> l4-group
// spreads 2-way over bank quads = free (m136). Fragment data bit-identical.
// vtb is sigma-permuted by proj, so the PV A-frag is one contiguous b128 chunk.
//
// R17: Q-tile 128 rows (2 q-groups per wave): each kf/vf LDS fragment feeds
// 2 MFMAs; LDS reads, staging bytes and barriers halve per FLOP.
// R18: complement pairing restored. R17's qtt=15-(bid>>5) gave CU group g
// blocks summing to 48-4g steps (2.4x imbalance, critical path 48 vs avg 34).
// Now bid<256 -> qtt=15-(bid>>5) (heavy), bid>=256 -> qtt=(bid>>5)-8 (light):
// each CU's pair sums to (32-2g)+(2g+2) = 34 steps, constant.
__global__ __launch_bounds__(256) void attn(
    const unsigned short* __restrict__ q,
    const unsigned short* __restrict__ k,
    const unsigned short* __restrict__ vt,
    unsigned short* __restrict__ y)
{
    __shared__ unsigned short sk[2][64 * 64];   // [s][d], chunk-swizzled
    __shared__ unsigned short sv[2][64 * 64];   // [d][s-perm], chunk-swizzled
    const int tid = threadIdx.x, wave = tid >> 6, lane = tid & 63;
    const int l15 = lane & 15, l4 = lane >> 4;
    const int bid = blockIdx.x;
    const int qtt = (bid < 256) ? (15 - (bid >> 5)) : ((bid >> 5) - 8);
    const int bh = bid & 31;
    const int nb = bh >> 4, hh = bh & 15;
    const int q0 = qtt << 7;                    // 128-row Q tile
    const size_t base = (size_t)bh << 17;

    // staging coordinates: wave w call j covers rows j*32 + w*8 .. +7
    const int lrow = lane >> 3;                           // 0..7 local row
    const int gch = ((lane & 7) ^ lrow) << 3;             // swizzled chunk (elems)
    const int row0 = wave * 8 + lrow, row1 = 32 + wave * 8 + lrow;
    const unsigned short* kg0 = &k[base + (size_t)row0 * 64 + gch];   // + s0*64
    const unsigned short* kg1 = &k[base + (size_t)row1 * 64 + gch];
    const unsigned short* vg0 = &vt[(size_t)((hh << 6) + row0) * 4096 + (nb << 11) + gch];
    const unsigned short* vg1 = &vt[(size_t)((hh << 6) + row1) * 4096 + (nb << 11) + gch];
    const int lbk0 = (wave * 8) * 64, lbk1 = (32 + wave * 8) * 64;  // wave-uniform

    // Q fragments (B-operand: n=l15 -> q row, k=l4*8..+7 -> d), once per block.
    // group g covers q rows q0 + 64g + wave*16 + l15.
    bf16x8 qf[2][2];
    #pragma unroll
    for (int g = 0; g < 2; ++g)
        #pragma unroll
        for (int ks = 0; ks < 2; ++ks)
            qf[g][ks] = *(const bf16x8*)
                &q[base + (size_t)(q0 + (g << 6) + wave * 16 + l15) * 64 + ks * 32 + l4 * 8];

    float l_sum[2] = {0.f, 0.f};
    f32x4 acc[2][4] = {};

    const int nst = 2 * qtt + 2;                // k-tiles covering s < (qtt+1)*128

    // read-side swizzled chunk offset for kf/vf (elements)
    const int rch0 = ((0 + l4) ^ (l15 & 7)) << 3;   // ks=0
    const int rch1 = ((4 + l4) ^ (l15 & 7)) << 3;   // ks=1

    // prologue: stage tile 0
    gload16(kg0, &sk[0][lbk0]);
    gload16(kg1, &sk[0][lbk1]);
    gload16(vg0, &sv[0][lbk0]);
    gload16(vg1, &sv[0][lbk1]);
    __syncthreads();

    // step body; LITERAL cur at each call site so all LDS bases fold to imms
    auto step = [&](const int cur, const int st, const bool more) {
        if (more) {
            const int nxt = cur ^ 1;
            const int s1e = (st + 1) << 6;              // element offset along s
            gload16(kg0 + ((size_t)s1e << 6), &sk[nxt][lbk0]);
            gload16(kg1 + ((size_t)s1e << 6), &sk[nxt][lbk1]);
            gload16(vg0 + s1e, &sv[nxt][lbk0]);
            gload16(vg1 + s1e, &sv[nxt][lbk1]);
        }

        f32x4 s_acc[2][4] = {};
        #pragma unroll
        for (int ns = 0; ns < 4; ++ns) {
            bf16x8 kf0 = *(const bf16x8*)&sk[cur][(ns * 16 + l15) * 64 + rch0];
            bf16x8 kf1 = *(const bf16x8*)&sk[cur][(ns * 16 + l15) * 64 + rch1];
            s_acc[0][ns] = MFMA_BF16(kf0, qf[0][0], s_acc[0][ns], 0, 0, 0);
            s_acc[0][ns] = MFMA_BF16(kf1, qf[0][1], s_acc[0][ns], 0, 0, 0);
            s_acc[1][ns] = MFMA_BF16(kf0, qf[1][0], s_acc[1][ns], 0, 0, 0);
            s_acc[1][ns] = MFMA_BF16(kf1, qf[1][1], s_acc[1][ns], 0, 0, 0);
        }

        // causal mask: only the last two tiles intersect the diagonal band.
        // global s = st*64 + ns*16 + l4*4 + r ; global q = q0 + 64g + wave*16 + l15
        if (st >= nst - 2) {
            const int sb = st << 6;
            #pragma unroll
            for (int g = 0; g < 2; ++g) {
                const int qlg = q0 + (g << 6) + wave * 16 + l15;
                #pragma unroll
                for (int ns = 0; ns < 4; ++ns)
                    #pragma unroll
                    for (int r = 0; r < 4; ++r)
                        if (sb + ns * 16 + l4 * 4 + r > qlg) s_acc[g][ns][r] = -1e30f;
            }
        }

        float pe[2][4][4];
        #pragma unroll
        for (int g = 0; g < 2; ++g)
            #pragma unroll
            for (int ns = 0; ns < 4; ++ns) {
                #pragma unroll
                for (int r = 0; r < 4; ++r) pe[g][ns][r] = exp2f(s_acc[g][ns][r]);
                l_sum[g] += (pe[g][ns][0] + pe[g][ns][1]) + (pe[g][ns][2] + pe[g][ns][3]);
            }

        #pragma unroll
        for (int ks = 0; ks < 2; ++ks) {
            bf16x8 pf0, pf1;
            {
                uint4 pw;
                pw.x = pk2t(pe[0][2 * ks][0], pe[0][2 * ks][1]);
                pw.y = pk2t(pe[0][2 * ks][2], pe[0][2 * ks][3]);
                pw.z = pk2t(pe[0][2 * ks + 1][0], pe[0][2 * ks + 1][1]);
                pw.w = pk2t(pe[0][2 * ks + 1][2], pe[0][2 * ks + 1][3]);
                pf0 = *(bf16x8*)&pw;
            }
            {
                uint4 pw;
                pw.x = pk2t(pe[1][2 * ks][0], pe[1][2 * ks][1]);
                pw.y = pk2t(pe[1][2 * ks][2], pe[1][2 * ks][3]);
                pw.z = pk2t(pe[1][2 * ks + 1][0], pe[1][2 * ks + 1][1]);
                pw.w = pk2t(pe[1][2 * ks + 1][2], pe[1][2 * ks + 1][3]);
                pf1 = *(bf16x8*)&pw;
            }
            const int rch = ks ? rch1 : rch0;
            #pragma unroll
            for (int ds = 0; ds < 4; ++ds) {
                bf16x8 vf = *(const bf16x8*)&sv[cur][(ds * 16 + l15) * 64 + rch];
                acc[0][ds] = MFMA_BF16(vf, pf0, acc[0][ds], 0, 0, 0);
                acc[1][ds] = MFMA_BF16(vf, pf1, acc[1][ds], 0, 0, 0);
            }
        }
        __syncthreads();   // next tile's gload16 deposits flew during compute
    };

    int st = 0;
    for (; st + 2 <= nst; st += 2) {
        step(0, st, true);
        step(1, st + 1, (st + 2) < nst);
    }
    if (st < nst) step(0, st, false);

    #pragma unroll
    for (int g = 0; g < 2; ++g) {
        float ls = l_sum[g];
        ls += __shfl_xor(ls, 16);
        ls += __shfl_xor(ls, 32);
        const float rl = __builtin_amdgcn_rcpf(ls);

        const size_t rowbase =
            ((size_t)((nb << 11) + q0 + (g << 6) + wave * 16 + l15) << 10) + (hh << 6) + l4 * 4;
        #pragma unroll
        for (int ds = 0; ds < 4; ++ds) {
            uint2 o;
            o.x = pk2(acc[g][ds][0] * rl, acc[g][ds][1] * rl);
            o.y = pk2(acc[g][ds][2] * rl, acc[g][ds][3] * rl);
            *(uint2*)&y[rowbase + ds * 16] = o;
        }
    }
}

extern "C" void kernel_launch(void* const* d_in, const int* in_sizes, int n_in,
                              void* d_out, int out_size, void* d_ws, size_t ws_size,
                              hipStream_t stream) {
    const float* x  = (const float*)d_in[0];
    const float* wq = (const float*)d_in[1];
    const float* wk = (const float*)d_in[2];
    const float* wv = (const float*)d_in[3];
    const float* wo = (const float*)d_in[4];
    float* out = (float*)d_out;

    const size_t M1 = 1u << 20;
    unsigned short* x16  = (unsigned short*)d_ws;          // 4M
    unsigned short* wq16 = x16 + 4 * M1;                   // 1M
    unsigned short* wk16 = wq16 + M1;
    unsigned short* wv16 = wk16 + M1;
    unsigned short* wot  = wv16 + M1;                      // 1M
    unsigned short* qbuf = wot + M1;                       // 4M [B,H,T,64]
    unsigned short* kbuf = qbuf + 4 * M1;                  // 4M
    unsigned short* vtb  = kbuf + 4 * M1;                  // 4M [1024][4096] sigma-perm
    unsigned short* ybuf = vtb + 4 * M1;                   // 4M [4096][1024]

    dim3 blk(256);
    prep<<<3840, blk, 0, stream>>>(x, wq, wk, wv, wo, x16, wq16, wk16, wv16, wot);
    proj<<<768, blk, 0, stream>>>(x16, wq16, wk16, wv16, qbuf, kbuf, vtb);
    attn<<<512, blk, 0, stream>>>(qbuf, kbuf, vtb, ybuf);
    outp<<<512, blk, 0, stream>>>(ybuf, wot, out);
}

// Round 3
// 175.681 us; speedup vs baseline: 1.0263x; 1.0263x over previous
//
#include <hip/hip_runtime.h>

// B=2, T=2048, C=1024, H=16, DQK=DV=64. Inputs fp32, output fp32, bf16 MFMA inside.

typedef short bf16x4 __attribute__((ext_vector_type(4)));
typedef short bf16x8 __attribute__((ext_vector_type(8)));
typedef float f32x4 __attribute__((ext_vector_type(4)));

#define MFMA_BF16 __builtin_amdgcn_mfma_f32_16x16x32_bf16

// log2(e)/8: Q pre-scale so softmax runs in base-2 domain (exp2 = bare v_exp_f32)
#define QSCALE 0.18033688011112042f

__device__ __forceinline__ unsigned short f2bf(float f) {
    union { float f; unsigned u; } un; un.f = f;
    unsigned r = un.u + 0x7fffu + ((un.u >> 16) & 1u);  // RNE
    return (unsigned short)(r >> 16);
}
__device__ __forceinline__ unsigned pk2(float a, float b) {
    return (unsigned)f2bf(a) | ((unsigned)f2bf(b) << 16);
}
// truncating pack of two floats into packed bf16x2: one v_perm_b32 (R19)
__device__ __forceinline__ unsigned pk2t(float a, float b) {
    union { float f; unsigned u; } ua, ub; ua.f = a; ub.f = b;
    return __builtin_amdgcn_perm(ub.u, ua.u, 0x07060302u);
}
__device__ __forceinline__ void gload16(const void* g, void* l) {
    __builtin_amdgcn_global_load_lds(
        (const __attribute__((address_space(1))) unsigned int*)g,
        (__attribute__((address_space(3))) unsigned int*)l, 16, 0, 0);
}

// ---------- fused prep: x/wq/wk/wv fp32->bf16, wo fp32->bf16 transposed ----------
__global__ __launch_bounds__(256) void prep(
    const float* __restrict__ x, const float* __restrict__ wq,
    const float* __restrict__ wk, const float* __restrict__ wv,
    const float* __restrict__ wo,
    unsigned short* __restrict__ x16, unsigned short* __restrict__ wq16,
    unsigned short* __restrict__ wk16, unsigned short* __restrict__ wv16,
    unsigned short* __restrict__ wot)
{
    const int bid = blockIdx.x;
    if (bid < 3584) {
        const float* s; unsigned short* d; int off;
        if (bid < 2048)      { s = x;  d = x16;  off = bid * 2048; }
        else if (bid < 2560) { s = wq; d = wq16; off = (bid - 2048) * 2048; }
        else if (bid < 3072) { s = wk; d = wk16; off = (bid - 2560) * 2048; }
        else                 { s = wv; d = wv16; off = (bid - 3072) * 2048; }
        int i = off + threadIdx.x * 8;
        float4 f0 = *(const float4*)&s[i], f1 = *(const float4*)&s[i + 4];
        uint4 o;
        o.x = pk2(f0.x, f0.y); o.y = pk2(f0.z, f0.w);
        o.z = pk2(f1.x, f1.y); o.w = pk2(f1.z, f1.w);
        *(uint4*)&d[i] = o;
    } else {
        // wo [K=1024][N=1024] -> wot [N][K] bf16
        __shared__ unsigned short t[64 * 72];
        const int b2 = bid - 3584;
        const int k0 = (b2 & 15) << 6, n0 = (b2 >> 4) << 6;
        const int r = threadIdx.x >> 2, cg = (threadIdx.x & 3) << 4;
        const float* src = &wo[(k0 + r) * 1024 + n0 + cg];
        #pragma unroll
        for (int j = 0; j < 16; j += 4) {
            float4 f = *(const float4*)&src[j];
            t[(cg + j + 0) * 72 + r] = f2bf(f.x);
            t[(cg + j + 1) * 72 + r] = f2bf(f.y);
            t[(cg + j + 2) * 72 + r] = f2bf(f.z);
            t[(cg + j + 3) * 72 + r] = f2bf(f.w);
        }
        __syncthreads();
        unsigned short* dst = &wot[(n0 + r) * 1024 + k0 + cg];
        unsigned short* tr = &t[r * 72 + cg];
        unsigned v[16];
        #pragma unroll
        for (int j = 0; j < 16; ++j) v[j] = tr[j];
        uint4 o0, o1;
        o0.x = v[0] | (v[1] << 16);   o0.y = v[2] | (v[3] << 16);
        o0.z = v[4] | (v[5] << 16);   o0.w = v[6] | (v[7] << 16);
        o1.x = v[8] | (v[9] << 16);   o1.y = v[10] | (v[11] << 16);
        o1.z = v[12] | (v[13] << 16); o1.w = v[14] | (v[15] << 16);
        *(uint4*)&dst[0] = o0;
        *(uint4*)&dst[8] = o1;
    }
}

// ---------- 128x128 bf16 GEMM, K=1024: BK=32 dbuf gload16, fully unrolled ----------
// R16 data-side XOR bank swizzle (validated): G-chunk = (lane&3) ^ ((r16>>1)&3);
// readers use chunk l4 ^ ((l15>>1)&3). mode 2 = vtb store with sigma permutation.
__device__ __forceinline__ void gemm_body(
    const unsigned short* __restrict__ A, const unsigned short* __restrict__ Bm,
    void* __restrict__ C, int m0, int n0, int mode, int ldc, float sc)
{
    __shared__ unsigned short sa[2][128 * 32];
    __shared__ unsigned short sb[2][128 * 32];
    const int tid = threadIdx.x, wave = tid >> 6, lane = tid & 63;
    const int l15 = lane & 15, l4 = lane >> 4;
    const int wm = (wave >> 1) << 6, wn = (wave & 1) << 6;

    const int r16 = lane >> 2;                               // 0..15
    const int gcol = (((lane & 3) ^ ((r16 >> 1) & 3)) << 3); // swizzled 16B chunk
    const int rcol = (l4 ^ ((l15 >> 1) & 3)) << 3;           // read-side chunk
    const unsigned short* Ag0 = &A[(size_t)(m0 + wave * 16 + r16) * 1024 + gcol];
    const unsigned short* Ag1 = Ag0 + (size_t)64 * 1024;
    const unsigned short* Bg0 = &Bm[(size_t)(n0 + wave * 16 + r16) * 1024 + gcol];
    const unsigned short* Bg1 = Bg0 + (size_t)64 * 1024;
    const int lb0 = (wave * 16) * 32;      // wave-uniform LDS bases (elements)
    const int lb1 = (64 + wave * 16) * 32;

    gload16(Ag0, &sa[0][lb0]);
    gload16(Ag1, &sa[0][lb1]);
    gload16(Bg0, &sb[0][lb0]);
    gload16(Bg1, &sb[0][lb1]);
    __syncthreads();

    f32x4 acc[4][4] = {};

    #pragma unroll
    for (int kk = 0; kk < 32; ++kk) {
        const int cur = kk & 1;
        if (kk < 31) {
            const int off = (kk + 1) * 32;
            const int nxt = 1 - cur;
            gload16(Ag0 + off, &sa[nxt][lb0]);
            gload16(Ag1 + off, &sa[nxt][lb1]);
            gload16(Bg0 + off, &sb[nxt][lb0]);
            gload16(Bg1 + off, &sb[nxt][lb1]);
        }
        bf16x8 af[4], bf4[4];
        #pragma unroll
        for (int i = 0; i < 4; ++i)
            af[i] = *(const bf16x8*)&sa[cur][(wm + i * 16 + l15) * 32 + rcol];
        #pragma unroll
        for (int j = 0; j < 4; ++j)
            bf4[j] = *(const bf16x8*)&sb[cur][(wn + j * 16 + l15) * 32 + rcol];
        #pragma unroll
        for (int i = 0; i < 4; ++i)
            #pragma unroll
            for (int j = 0; j < 4; ++j)
                acc[i][j] = MFMA_BF16(af[i], bf4[j], acc[i][j], 0, 0, 0);
        __syncthreads();   // next-slab loads have flown during the MFMAs above
    }

    #pragma unroll
    for (int i = 0; i < 4; ++i)
        #pragma unroll
        for (int j = 0; j < 4; ++j)
            #pragma unroll
            for (int r = 0; r < 4; ++r) {
                int row = m0 + wm + i * 16 + l4 * 4 + r;
                int col = n0 + wn + j * 16 + l15;
                float val = acc[i][j][r];
                if (mode == 0) {
                    int nb = row >> 11, t = row & 2047;
                    int hh = col >> 6, dd = col & 63;
                    ((unsigned short*)C)[(((nb << 4) + hh) * 2048 + t) * 64 + dd] =
                        f2bf(val * sc);
                } else if (mode == 1) {
                    ((float*)C)[(size_t)row * ldc + col] = val;
                } else {
                    // sigma permutation within each 32-col block (see R15)
                    int s = col & 31;
                    int cp = (col & ~31) | (((s >> 2) & 3) << 3)
                                         | (((s >> 4) & 1) << 2) | (s & 3);
                    ((unsigned short*)C)[(size_t)row * ldc + cp] = f2bf(val);
                }
            }
}

// grid 768: [0,512) QK fused | [512,768) V^T = Wv @ X^T (sigma-permuted cols)
__global__ __launch_bounds__(256) void proj(
    const unsigned short* __restrict__ x16,
    const unsigned short* __restrict__ wq16,
    const unsigned short* __restrict__ wk16,
    const unsigned short* __restrict__ wv16,
    unsigned short* __restrict__ qbuf,
    unsigned short* __restrict__ kbuf,
    unsigned short* __restrict__ vtb)
{
    const int bid = blockIdx.x;
    if (bid < 512) {
        int m0 = (bid & 31) << 7;
        int n0g = (bid >> 5) << 7;
        if (n0g < 1024)
            gemm_body(x16, wq16, qbuf, m0, n0g, 0, 0, QSCALE);
        else
            gemm_body(x16, wk16, kbuf, m0, n0g - 1024, 0, 0, 1.0f);
    } else {
        int v = bid - 512;
        gemm_body(wv16, x16, vtb, (v & 7) << 7, (v >> 3) << 7, 2, 4096, 1.0f);
    }
}

// ---------- out = Y @ Wo^T: 128x128 gemm_body tiles, grid 256 (R17 config) ----------
// R18's 128x64/grid-512 measured ~6.5us WORSE (doubled A traffic, no overlap win).
// Reverted to the measured-best variant.
__global__ __launch_bounds__(256) void outp(
    const unsigned short* __restrict__ ybuf,
    const unsigned short* __restrict__ wot,
    float* __restrict__ out)
{
    const int bid = blockIdx.x;
    gemm_body(ybuf, wot, out, (bid & 31) << 7, (bid >> 5) << 7, 1, 1024, 1.0f);
}

// ---------- flash causal attention: S^T form, counted-vmcnt 3-buffer pipeline ----------
// K and V^T rows are 128B-contiguous in global: global_load_lds stages them
// directly into packed [row][64] tiles. Data-side XOR chunk swizzle (validated).
// vtb is sigma-permuted by proj, so the PV A-frag is one contiguous b128 chunk.
//
// R17: 128-row Q tiles, 2 q-groups/wave (each kf/vf fragment feeds 2 MFMAs).
// R19: __syncthreads forced vmcnt(0) every step -> ~2600cyc/step exposed drain
// (MfmaUtil 13.7, VALU 44, step time 3500cyc vs ~700 compute). Now: 3 LDS
// buffers, stage tile t+2 at top of step t, end step with s_waitcnt vmcnt(4)
// (newest 4 loads STAY IN FLIGHT across the barrier) + raw s_barrier. Load
// latency gets 2 full compute phases to hide under (T3/T4, m218: +38-73%).
// Hazards: write target (t+2)%3 is disjoint from buffers in use (t, t+1);
// per-step barrier bounds wave skew to <1 step; each wave drains its OWN
// stage(t+1) loads (vmcnt(4)) before the barrier that publishes them.
__global__ __launch_bounds__(256) void attn(
    const unsigned short* __restrict__ q,
    const unsigned short* __restrict__ k,
    const unsigned short* __restrict__ vt,
    unsigned short* __restrict__ y)
{
    __shared__ unsigned short sk[3][64 * 64];   // [s][d], chunk-swizzled
    __shared__ unsigned short sv[3][64 * 64];   // [d][s-perm], chunk-swizzled
    const int tid = threadIdx.x, wave = tid >> 6, lane = tid & 63;
    const int l15 = lane & 15, l4 = lane >> 4;
    const int bid = blockIdx.x;
    const int qtt = (bid < 256) ? (15 - (bid >> 5)) : ((bid >> 5) - 8);
    const int bh = bid & 31;
    const int nb = bh >> 4, hh = bh & 15;
    const int q0 = qtt << 7;                    // 128-row Q tile
    const size_t base = (size_t)bh << 17;

    // staging coordinates: wave w covers rows w*8..+7 and 32+w*8..+7
    const int lrow = lane >> 3;                           // 0..7 local row
    const int gch = ((lane & 7) ^ lrow) << 3;             // swizzled chunk (elems)
    const int row0 = wave * 8 + lrow, row1 = 32 + wave * 8 + lrow;
    const unsigned short* kg0 = &k[base + (size_t)row0 * 64 + gch];
    const unsigned short* kg1 = &k[base + (size_t)row1 * 64 + gch];
    const unsigned short* vg0 = &vt[(size_t)((hh << 6) + row0) * 4096 + (nb << 11) + gch];
    const unsigned short* vg1 = &vt[(size_t)((hh << 6) + row1) * 4096 + (nb << 11) + gch];
    const int lbk0 = (wave * 8) * 64, lbk1 = (32 + wave * 8) * 64;  // wave-uniform

    // Q fragments (B-operand: n=l15 -> q row, k=l4*8..+7 -> d), once per block.
    // group g covers q rows q0 + 64g + wave*16 + l15.
    bf16x8 qf[2][2];
    #pragma unroll
    for (int g = 0; g < 2; ++g)
        #pragma unroll
        for (int ks = 0; ks < 2; ++ks)
            qf[g][ks] = *(const bf16x8*)
                &q[base + (size_t)(q0 + (g << 6) + wave * 16 + l15) * 64 + ks * 32 + l4 * 8];
    // Drain qf loads NOW so the compiler never needs an in-loop vmcnt for them;
    // after this point the only outstanding VMEM ops are our counted gload16s.
    asm volatile("s_waitcnt vmcnt(0)" ::: "memory");

    float l_sum[2] = {0.f, 0.f};
    f32x4 acc[2][4] = {};

    const int nst = 2 * qtt + 2;                // k-tiles covering s < (qtt+1)*128

    // read-side swizzled chunk offset for kf/vf (elements)
    const int rch0 = ((0 + l4) ^ (l15 & 7)) << 3;   // ks=0
    const int rch1 = ((4 + l4) ^ (l15 & 7)) << 3;   // ks=1

    // stage k-tile st into buffer sbuf (literal sbuf at every call site)
    auto stage = [&](const int sbuf, const int st) {
        const size_t ko = (size_t)st << 12;     // 64 rows x 64 elems
        const int vo = st << 6;                 // 64 columns
        gload16(kg0 + ko, &sk[sbuf][lbk0]);
        gload16(kg1 + ko, &sk[sbuf][lbk1]);
        gload16(vg0 + vo, &sv[sbuf][lbk0]);
        gload16(vg1 + vo, &sv[sbuf][lbk1]);
    };

    // prologue: stage tiles 0,1 (nst >= 2 always); publish 0, keep 1 in flight
    stage(0, 0);
    stage(1, 1);
    asm volatile("s_waitcnt vmcnt(4)" ::: "memory");
    __builtin_amdgcn_s_barrier();
    asm volatile("" ::: "memory");

    // step body; LITERAL cur/nxt at each call site so LDS bases fold to imms
    auto step = [&](const int cur, const int nxt, const int st) {
        const bool issue = (st + 2) < nst;
        if (issue) stage(nxt, st + 2);

        f32x4 s_acc[2][4] = {};
        #pragma unroll
        for (int ns = 0; ns < 4; ++ns) {
            bf16x8 kf0 = *(const bf16x8*)&sk[cur][(ns * 16 + l15) * 64 + rch0];
            bf16x8 kf1 = *(const bf16x8*)&sk[cur][(ns * 16 + l15) * 64 + rch1];
            s_acc[0][ns] = MFMA_BF16(kf0, qf[0][0], s_acc[0][ns], 0, 0, 0);
            s_acc[0][ns] = MFMA_BF16(kf1, qf[0][1], s_acc[0][ns], 0, 0, 0);
            s_acc[1][ns] = MFMA_BF16(kf0, qf[1][0], s_acc[1][ns], 0, 0, 0);
            s_acc[1][ns] = MFMA_BF16(kf1, qf[1][1], s_acc[1][ns], 0, 0, 0);
        }

        // causal mask: only the last two tiles intersect the diagonal band.
        if (st >= nst - 2) {
            const int sb = st << 6;
            #pragma unroll
            for (int g = 0; g < 2; ++g) {
                const int qlg = q0 + (g << 6) + wave * 16 + l15;
                #pragma unroll
                for (int ns = 0; ns < 4; ++ns)
                    #pragma unroll
                    for (int r = 0; r < 4; ++r)
                        if (sb + ns * 16 + l4 * 4 + r > qlg) s_acc[g][ns][r] = -1e30f;
            }
        }

        float pe[2][4][4];
        #pragma unroll
        for (int g = 0; g < 2; ++g)
            #pragma unroll
            for (int ns = 0; ns < 4; ++ns) {
                #pragma unroll
                for (int r = 0; r < 4; ++r) pe[g][ns][r] = exp2f(s_acc[g][ns][r]);
                l_sum[g] += (pe[g][ns][0] + pe[g][ns][1]) + (pe[g][ns][2] + pe[g][ns][3]);
            }

        #pragma unroll
        for (int ks = 0; ks < 2; ++ks) {
            bf16x8 pf0, pf1;
            {
                uint4 pw;
                pw.x = pk2t(pe[0][2 * ks][0], pe[0][2 * ks][1]);
                pw.y = pk2t(pe[0][2 * ks][2], pe[0][2 * ks][3]);
                pw.z = pk2t(pe[0][2 * ks + 1][0], pe[0][2 * ks + 1][1]);
                pw.w = pk2t(pe[0][2 * ks + 1][2], pe[0][2 * ks + 1][3]);
                pf0 = *(bf16x8*)&pw;
            }
            {
                uint4 pw;
                pw.x = pk2t(pe[1][2 * ks][0], pe[1][2 * ks][1]);
                pw.y = pk2t(pe[1][2 * ks][2], pe[1][2 * ks][3]);
                pw.z = pk2t(pe[1][2 * ks + 1][0], pe[1][2 * ks + 1][1]);
                pw.w = pk2t(pe[1][2 * ks + 1][2], pe[1][2 * ks + 1][3]);
                pf1 = *(bf16x8*)&pw;
            }
            const int rch = ks ? rch1 : rch0;
            #pragma unroll
            for (int ds = 0; ds < 4; ++ds) {
                bf16x8 vf = *(const bf16x8*)&sv[cur][(ds * 16 + l15) * 64 + rch];
                acc[0][ds] = MFMA_BF16(vf, pf0, acc[0][ds], 0, 0, 0);
                acc[1][ds] = MFMA_BF16(vf, pf1, acc[1][ds], 0, 0, 0);
            }
        }

        // publish stage(st+1) (drain it: it is the oldest 4 outstanding),
        // keep stage(st+2)'s 4 loads in flight across the barrier.
        if (issue) asm volatile("s_waitcnt vmcnt(4)" ::: "memory");
        else       asm volatile("s_waitcnt vmcnt(0)" ::: "memory");
        __builtin_amdgcn_s_barrier();
        asm volatile("" ::: "memory");
    };

    int st = 0;
    for (; st + 3 <= nst; st += 3) {
        step(0, 2, st);
        step(1, 0, st + 1);
        step(2, 1, st + 2);
    }
    if (st < nst) {
        step(0, 2, st);
        if (st + 1 < nst) step(1, 0, st + 1);
    }

    #pragma unroll
    for (int g = 0; g < 2; ++g) {
        float ls = l_sum[g];
        ls += __shfl_xor(ls, 16);
        ls += __shfl_xor(ls, 32);
        const float rl = __builtin_amdgcn_rcpf(ls);

        const size_t rowbase =
            ((size_t)((nb << 11) + q0 + (g << 6) + wave * 16 + l15) << 10) + (hh << 6) + l4 * 4;
        #pragma unroll
        for (int ds = 0; ds < 4; ++ds) {
            uint2 o;
            o.x = pk2(acc[g][ds][0] * rl, acc[g][ds][1] * rl);
            o.y = pk2(acc[g][ds][2] * rl, acc[g][ds][3] * rl);
            *(uint2*)&y[rowbase + ds * 16] = o;
        }
    }
}

extern "C" void kernel_launch(void* const* d_in, const int* in_sizes, int n_in,
                              void* d_out, int out_size, void* d_ws, size_t ws_size,
                              hipStream_t stream) {
    const float* x  = (const float*)d_in[0];
    const float* wq = (const float*)d_in[1];
    const float* wk = (const float*)d_in[2];
    const float* wv = (const float*)d_in[3];
    const float* wo = (const float*)d_in[4];
    float* out = (float*)d_out;

    const size_t M1 = 1u << 20;
    unsigned short* x16  = (unsigned short*)d_ws;          // 4M
    unsigned short* wq16 = x16 + 4 * M1;                   // 1M
    unsigned short* wk16 = wq16 + M1;
    unsigned short* wv16 = wk16 + M1;
    unsigned short* wot  = wv16 + M1;                      // 1M
    unsigned short* qbuf = wot + M1;                       // 4M [B,H,T,64]
    unsigned short* kbuf = qbuf + 4 * M1;                  // 4M
    unsigned short* vtb  = kbuf + 4 * M1;                  // 4M [1024][4096] sigma-perm
    unsigned short* ybuf = vtb + 4 * M1;                   // 4M [4096][1024]

    dim3 blk(256);
    prep<<<3840, blk, 0, stream>>>(x, wq, wk, wv, wo, x16, wq16, wk16, wv16, wot);
    proj<<<768, blk, 0, stream>>>(x16, wq16, wk16, wv16, qbuf, kbuf, vtb);
    attn<<<512, blk, 0, stream>>>(qbuf, kbuf, vtb, ybuf);
    outp<<<256, blk, 0, stream>>>(ybuf, wot, out);
}

// Round 4
// 173.652 us; speedup vs baseline: 1.0383x; 1.0117x over previous
//
#include <hip/hip_runtime.h>

// B=2, T=2048, C=1024, H=16, DQK=DV=64. Inputs fp32, output fp32, bf16 MFMA inside.

typedef short bf16x4 __attribute__((ext_vector_type(4)));
typedef short bf16x8 __attribute__((ext_vector_type(8)));
typedef float f32x4 __attribute__((ext_vector_type(4)));

#define MFMA_BF16 __builtin_amdgcn_mfma_f32_16x16x32_bf16

// log2(e)/8: Q pre-scale so softmax runs in base-2 domain (exp2 = bare v_exp_f32)
#define QSCALE 0.18033688011112042f

__device__ __forceinline__ unsigned short f2bf(float f) {
    union { float f; unsigned u; } un; un.f = f;
    unsigned r = un.u + 0x7fffu + ((un.u >> 16) & 1u);  // RNE
    return (unsigned short)(r >> 16);
}
__device__ __forceinline__ unsigned pk2(float a, float b) {
    return (unsigned)f2bf(a) | ((unsigned)f2bf(b) << 16);
}
// truncating pack of two floats into packed bf16x2: one v_perm_b32 (R19)
__device__ __forceinline__ unsigned pk2t(float a, float b) {
    union { float f; unsigned u; } ua, ub; ua.f = a; ub.f = b;
    return __builtin_amdgcn_perm(ub.u, ua.u, 0x07060302u);
}
__device__ __forceinline__ void gload16(const void* g, void* l) {
    __builtin_amdgcn_global_load_lds(
        (const __attribute__((address_space(1))) unsigned int*)g,
        (__attribute__((address_space(3))) unsigned int*)l, 16, 0, 0);
}

// ---------- fused prep: x/wq/wk/wv fp32->bf16, wo fp32->bf16 transposed ----------
__global__ __launch_bounds__(256) void prep(
    const float* __restrict__ x, const float* __restrict__ wq,
    const float* __restrict__ wk, const float* __restrict__ wv,
    const float* __restrict__ wo,
    unsigned short* __restrict__ x16, unsigned short* __restrict__ wq16,
    unsigned short* __restrict__ wk16, unsigned short* __restrict__ wv16,
    unsigned short* __restrict__ wot)
{
    const int bid = blockIdx.x;
    if (bid < 3584) {
        const float* s; unsigned short* d; int off;
        if (bid < 2048)      { s = x;  d = x16;  off = bid * 2048; }
        else if (bid < 2560) { s = wq; d = wq16; off = (bid - 2048) * 2048; }
        else if (bid < 3072) { s = wk; d = wk16; off = (bid - 2560) * 2048; }
        else                 { s = wv; d = wv16; off = (bid - 3072) * 2048; }
        int i = off + threadIdx.x * 8;
        float4 f0 = *(const float4*)&s[i], f1 = *(const float4*)&s[i + 4];
        uint4 o;
        o.x = pk2(f0.x, f0.y); o.y = pk2(f0.z, f0.w);
        o.z = pk2(f1.x, f1.y); o.w = pk2(f1.z, f1.w);
        *(uint4*)&d[i] = o;
    } else {
        // wo [K=1024][N=1024] -> wot [N][K] bf16
        __shared__ unsigned short t[64 * 72];
        const int b2 = bid - 3584;
        const int k0 = (b2 & 15) << 6, n0 = (b2 >> 4) << 6;
        const int r = threadIdx.x >> 2, cg = (threadIdx.x & 3) << 4;
        const float* src = &wo[(k0 + r) * 1024 + n0 + cg];
        #pragma unroll
        for (int j = 0; j < 16; j += 4) {
            float4 f = *(const float4*)&src[j];
            t[(cg + j + 0) * 72 + r] = f2bf(f.x);
            t[(cg + j + 1) * 72 + r] = f2bf(f.y);
            t[(cg + j + 2) * 72 + r] = f2bf(f.z);
            t[(cg + j + 3) * 72 + r] = f2bf(f.w);
        }
        __syncthreads();
        unsigned short* dst = &wot[(n0 + r) * 1024 + k0 + cg];
        unsigned short* tr = &t[r * 72 + cg];
        unsigned v[16];
        #pragma unroll
        for (int j = 0; j < 16; ++j) v[j] = tr[j];
        uint4 o0, o1;
        o0.x = v[0] | (v[1] << 16);   o0.y = v[2] | (v[3] << 16);
        o0.z = v[4] | (v[5] << 16);   o0.w = v[6] | (v[7] << 16);
        o1.x = v[8] | (v[9] << 16);   o1.y = v[10] | (v[11] << 16);
        o1.z = v[12] | (v[13] << 16); o1.w = v[14] | (v[15] << 16);
        *(uint4*)&dst[0] = o0;
        *(uint4*)&dst[8] = o1;
    }
}

// ---------- 128x128 bf16 GEMM, K=1024: BK=32 dbuf gload16, fully unrolled ----------
// R16 data-side XOR bank swizzle (validated): G-chunk = (lane&3) ^ ((r16>>1)&3);
// readers use chunk l4 ^ ((l15>>1)&3). mode 2 = vtb store with sigma permutation.
__device__ __forceinline__ void gemm_body(
    const unsigned short* __restrict__ A, const unsigned short* __restrict__ Bm,
    void* __restrict__ C, int m0, int n0, int mode, int ldc, float sc)
{
    __shared__ unsigned short sa[2][128 * 32];
    __shared__ unsigned short sb[2][128 * 32];
    const int tid = threadIdx.x, wave = tid >> 6, lane = tid & 63;
    const int l15 = lane & 15, l4 = lane >> 4;
    const int wm = (wave >> 1) << 6, wn = (wave & 1) << 6;

    const int r16 = lane >> 2;                               // 0..15
    const int gcol = (((lane & 3) ^ ((r16 >> 1) & 3)) << 3); // swizzled 16B chunk
    const int rcol = (l4 ^ ((l15 >> 1) & 3)) << 3;           // read-side chunk
    const unsigned short* Ag0 = &A[(size_t)(m0 + wave * 16 + r16) * 1024 + gcol];
    const unsigned short* Ag1 = Ag0 + (size_t)64 * 1024;
    const unsigned short* Bg0 = &Bm[(size_t)(n0 + wave * 16 + r16) * 1024 + gcol];
    const unsigned short* Bg1 = Bg0 + (size_t)64 * 1024;
    const int lb0 = (wave * 16) * 32;      // wave-uniform LDS bases (elements)
    const int lb1 = (64 + wave * 16) * 32;

    gload16(Ag0, &sa[0][lb0]);
    gload16(Ag1, &sa[0][lb1]);
    gload16(Bg0, &sb[0][lb0]);
    gload16(Bg1, &sb[0][lb1]);
    __syncthreads();

    f32x4 acc[4][4] = {};

    #pragma unroll
    for (int kk = 0; kk < 32; ++kk) {
        const int cur = kk & 1;
        if (kk < 31) {
            const int off = (kk + 1) * 32;
            const int nxt = 1 - cur;
            gload16(Ag0 + off, &sa[nxt][lb0]);
            gload16(Ag1 + off, &sa[nxt][lb1]);
            gload16(Bg0 + off, &sb[nxt][lb0]);
            gload16(Bg1 + off, &sb[nxt][lb1]);
        }
        bf16x8 af[4], bf4[4];
        #pragma unroll
        for (int i = 0; i < 4; ++i)
            af[i] = *(const bf16x8*)&sa[cur][(wm + i * 16 + l15) * 32 + rcol];
        #pragma unroll
        for (int j = 0; j < 4; ++j)
            bf4[j] = *(const bf16x8*)&sb[cur][(wn + j * 16 + l15) * 32 + rcol];
        #pragma unroll
        for (int i = 0; i < 4; ++i)
            #pragma unroll
            for (int j = 0; j < 4; ++j)
                acc[i][j] = MFMA_BF16(af[i], bf4[j], acc[i][j], 0, 0, 0);
        __syncthreads();   // next-slab loads have flown during the MFMAs above
    }

    #pragma unroll
    for (int i = 0; i < 4; ++i)
        #pragma unroll
        for (int j = 0; j < 4; ++j)
            #pragma unroll
            for (int r = 0; r < 4; ++r) {
                int row = m0 + wm + i * 16 + l4 * 4 + r;
                int col = n0 + wn + j * 16 + l15;
                float val = acc[i][j][r];
                if (mode == 0) {
                    int nb = row >> 11, t = row & 2047;
                    int hh = col >> 6, dd = col & 63;
                    ((unsigned short*)C)[(((nb << 4) + hh) * 2048 + t) * 64 + dd] =
                        f2bf(val * sc);
                } else if (mode == 1) {
                    ((float*)C)[(size_t)row * ldc + col] = val;
                } else {
                    // sigma permutation within each 32-col block (see R15)
                    int s = col & 31;
                    int cp = (col & ~31) | (((s >> 2) & 3) << 3)
                                         | (((s >> 4) & 1) << 2) | (s & 3);
                    ((unsigned short*)C)[(size_t)row * ldc + cp] = f2bf(val);
                }
            }
}

// grid 768: [0,512) QK fused | [512,768) V^T = Wv @ X^T (sigma-permuted cols)
__global__ __launch_bounds__(256) void proj(
    const unsigned short* __restrict__ x16,
    const unsigned short* __restrict__ wq16,
    const unsigned short* __restrict__ wk16,
    const unsigned short* __restrict__ wv16,
    unsigned short* __restrict__ qbuf,
    unsigned short* __restrict__ kbuf,
    unsigned short* __restrict__ vtb)
{
    const int bid = blockIdx.x;
    if (bid < 512) {
        int m0 = (bid & 31) << 7;
        int n0g = (bid >> 5) << 7;
        if (n0g < 1024)
            gemm_body(x16, wq16, qbuf, m0, n0g, 0, 0, QSCALE);
        else
            gemm_body(x16, wk16, kbuf, m0, n0g - 1024, 0, 0, 1.0f);
    } else {
        int v = bid - 512;
        gemm_body(wv16, x16, vtb, (v & 7) << 7, (v >> 3) << 7, 2, 4096, 1.0f);
    }
}

// ---------- out = Y @ Wo^T: 128x128 gemm_body tiles, grid 256 (R17 best) ----------
__global__ __launch_bounds__(256) void outp(
    const unsigned short* __restrict__ ybuf,
    const unsigned short* __restrict__ wot,
    float* __restrict__ out)
{
    const int bid = blockIdx.x;
    gemm_body(ybuf, wot, out, (bid & 31) << 7, (bid >> 5) << 7, 1, 1024, 1.0f);
}

// ---------- flash causal attention: in-block split-K, 8 waves (R20) ----------
// R19 post-mortem: counted-vmcnt pipeline gave 0 (loads are L2-hits, FETCH=12MB).
// Real bottleneck: heavy blocks run SOLO at 4 waves/CU = 1 wave/SIMD, so the
// serial QK->exp2->pack->PV chain (~3400cyc/step vs ~700 issue) is fully
// exposed -- no co-resident wave to hide under.
// R20: 512-thread blocks. Waves 0-3 (wk2=0) process even k-tiles, waves 4-7
// (wk2=1) odd k-tiles, private (acc,l_sum) partials (exp2-domain sums add
// linearly; no max tracking -> merge is an exact f32 add via LDS). Even a solo
// heavy block now keeps 2 independent waves/SIMD; supersteps halve (32->16).
// Staging: 512 threads cover a full 64x64 tile per gload16 call; dbuf,
// plain __syncthreads. LDS 64KB -> 2 blocks/CU; launch_bounds(512,4) caps
// VGPR at 128 so both blocks fit. Complement pairing kept (sumsteps=17/CU).
__global__ __launch_bounds__(512, 4) void attn(
    const unsigned short* __restrict__ q,
    const unsigned short* __restrict__ k,
    const unsigned short* __restrict__ vt,
    unsigned short* __restrict__ y)
{
    __shared__ unsigned short sk[2][2][64 * 64];   // [stage][parity][s][d]
    __shared__ unsigned short sv[2][2][64 * 64];   // [stage][parity][d][s-perm]
    const int tid = threadIdx.x, wave = tid >> 6, lane = tid & 63;
    const int ws = wave & 3, wk2 = wave >> 2;      // row-slice, k-parity
    const int l15 = lane & 15, l4 = lane >> 4;
    const int bid = blockIdx.x;
    const int qtt = (bid < 256) ? (15 - (bid >> 5)) : ((bid >> 5) - 8);
    const int bh = bid & 31;
    const int nb = bh >> 4, hh = bh & 15;
    const int q0 = qtt << 7;                    // 128-row Q tile
    const size_t base = (size_t)bh << 17;

    // staging: 8 waves x 8 rows cover all 64 rows of a tile in ONE gload16 call
    const int lrow = lane >> 3;                           // 0..7 local row
    const int gch = ((lane & 7) ^ lrow) << 3;             // swizzled chunk (elems)
    const int row = wave * 8 + lrow;                      // 0..63
    const unsigned short* kg = &k[base + (size_t)row * 64 + gch];
    const unsigned short* vg = &vt[(size_t)((hh << 6) + row) * 4096 + (nb << 11) + gch];
    const int lb = (wave * 8) * 64;                       // wave-uniform LDS base

    // Q fragments (B-operand: n=l15 -> q row, k=l4*8..+7 -> d), once per block.
    // group g covers q rows q0 + 64g + ws*16 + l15 (both parities load same Q).
    bf16x8 qf[2][2];
    #pragma unroll
    for (int g = 0; g < 2; ++g)
        #pragma unroll
        for (int ks = 0; ks < 2; ++ks)
            qf[g][ks] = *(const bf16x8*)
                &q[base + (size_t)(q0 + (g << 6) + ws * 16 + l15) * 64 + ks * 32 + l4 * 8];

    float l_sum[2] = {0.f, 0.f};
    f32x4 acc[2][4] = {};

    const int nsup = qtt + 1;                   // supersteps; tiles 2p, 2p+1

    // read-side swizzled chunk offset for kf/vf (elements)
    const int rch0 = ((0 + l4) ^ (l15 & 7)) << 3;   // ks=0
    const int rch1 = ((4 + l4) ^ (l15 & 7)) << 3;   // ks=1

    // stage both tiles of superstep p into stage sbuf
    auto stage_pair = [&](const int sbuf, const int p) {
        gload16(kg + ((size_t)p << 13),        &sk[sbuf][0][lb]);   // tile 2p
        gload16(kg + ((size_t)p << 13) + 4096, &sk[sbuf][1][lb]);   // tile 2p+1
        gload16(vg + (p << 7),      &sv[sbuf][0][lb]);
        gload16(vg + (p << 7) + 64, &sv[sbuf][1][lb]);
    };

    stage_pair(0, 0);
    __syncthreads();

    // superstep body; LITERAL cur at each call site so LDS bases fold to imms
    auto sstep = [&](const int cur, const int p) {
        if (p + 1 < nsup) stage_pair(cur ^ 1, p + 1);
        const int st = 2 * p + wk2;
        const unsigned short* skc = &sk[cur][wk2][0];
        const unsigned short* svc = &sv[cur][wk2][0];

        f32x4 s_acc[2][4] = {};
        #pragma unroll
        for (int ns = 0; ns < 4; ++ns) {
            bf16x8 kf0 = *(const bf16x8*)&skc[(ns * 16 + l15) * 64 + rch0];
            bf16x8 kf1 = *(const bf16x8*)&skc[(ns * 16 + l15) * 64 + rch1];
            s_acc[0][ns] = MFMA_BF16(kf0, qf[0][0], s_acc[0][ns], 0, 0, 0);
            s_acc[0][ns] = MFMA_BF16(kf1, qf[0][1], s_acc[0][ns], 0, 0, 0);
            s_acc[1][ns] = MFMA_BF16(kf0, qf[1][0], s_acc[1][ns], 0, 0, 0);
            s_acc[1][ns] = MFMA_BF16(kf1, qf[1][1], s_acc[1][ns], 0, 0, 0);
        }

        // causal mask: both parities touch the diagonal band only at p==nsup-1
        if (p == nsup - 1) {
            const int sb = st << 6;
            #pragma unroll
            for (int g = 0; g < 2; ++g) {
                const int qlg = q0 + (g << 6) + ws * 16 + l15;
                #pragma unroll
                for (int ns = 0; ns < 4; ++ns)
                    #pragma unroll
                    for (int r = 0; r < 4; ++r)
                        if (sb + ns * 16 + l4 * 4 + r > qlg) s_acc[g][ns][r] = -1e30f;
            }
        }

        float pe[2][4][4];
        #pragma unroll
        for (int g = 0; g < 2; ++g)
            #pragma unroll
            for (int ns = 0; ns < 4; ++ns) {
                #pragma unroll
                for (int r = 0; r < 4; ++r) pe[g][ns][r] = exp2f(s_acc[g][ns][r]);
                l_sum[g] += (pe[g][ns][0] + pe[g][ns][1]) + (pe[g][ns][2] + pe[g][ns][3]);
            }

        #pragma unroll
        for (int ks = 0; ks < 2; ++ks) {
            bf16x8 pf0, pf1;
            {
                uint4 pw;
                pw.x = pk2t(pe[0][2 * ks][0], pe[0][2 * ks][1]);
                pw.y = pk2t(pe[0][2 * ks][2], pe[0][2 * ks][3]);
                pw.z = pk2t(pe[0][2 * ks + 1][0], pe[0][2 * ks + 1][1]);
                pw.w = pk2t(pe[0][2 * ks + 1][2], pe[0][2 * ks + 1][3]);
                pf0 = *(bf16x8*)&pw;
            }
            {
                uint4 pw;
                pw.x = pk2t(pe[1][2 * ks][0], pe[1][2 * ks][1]);
                pw.y = pk2t(pe[1][2 * ks][2], pe[1][2 * ks][3]);
                pw.z = pk2t(pe[1][2 * ks + 1][0], pe[1][2 * ks + 1][1]);
                pw.w = pk2t(pe[1][2 * ks + 1][2], pe[1][2 * ks + 1][3]);
                pf1 = *(bf16x8*)&pw;
            }
            const int rch = ks ? rch1 : rch0;
            #pragma unroll
            for (int ds = 0; ds < 4; ++ds) {
                bf16x8 vf = *(const bf16x8*)&svc[(ds * 16 + l15) * 64 + rch];
                acc[0][ds] = MFMA_BF16(vf, pf0, acc[0][ds], 0, 0, 0);
                acc[1][ds] = MFMA_BF16(vf, pf1, acc[1][ds], 0, 0, 0);
            }
        }
        __syncthreads();   // next pair's gload16 deposits flew during compute
    };

    int p = 0;
    for (; p + 2 <= nsup; p += 2) {
        sstep(0, p);
        sstep(1, p + 1);
    }
    if (p < nsup) sstep(0, p);

    // ---- cross-parity merge through LDS (exact f32 adds; one-time cost) ----
    // chunk-XOR by lane&7 spreads the [lane][32-float] layout over 8 bank-quads.
    float* mrg = (float*)&sk[0][0][0];          // 8192 floats = 32 KB
    float* lsr = (float*)&sv[0][0][0];
    const int mb = ((ws << 6) + lane) << 5;
    if (wk2 == 1) {
        #pragma unroll
        for (int g = 0; g < 2; ++g)
            #pragma unroll
            for (int ds = 0; ds < 4; ++ds) {
                const int c = g * 4 + ds;
                *(f32x4*)&mrg[mb + ((c ^ (lane & 7)) << 2)] = acc[g][ds];
            }
        lsr[(((ws << 6) + lane) << 1) + 0] = l_sum[0];
        lsr[(((ws << 6) + lane) << 1) + 1] = l_sum[1];
    }
    __syncthreads();
    if (wk2 == 0) {
        #pragma unroll
        for (int g = 0; g < 2; ++g)
            #pragma unroll
            for (int ds = 0; ds < 4; ++ds) {
                const int c = g * 4 + ds;
                f32x4 o = *(const f32x4*)&mrg[mb + ((c ^ (lane & 7)) << 2)];
                acc[g][ds] += o;
            }
        l_sum[0] += lsr[(((ws << 6) + lane) << 1) + 0];
        l_sum[1] += lsr[(((ws << 6) + lane) << 1) + 1];

        #pragma unroll
        for (int g = 0; g < 2; ++g) {
            float ls = l_sum[g];
            ls += __shfl_xor(ls, 16);
            ls += __shfl_xor(ls, 32);
            const float rl = __builtin_amdgcn_rcpf(ls);

            const size_t rowbase =
                ((size_t)((nb << 11) + q0 + (g << 6) + ws * 16 + l15) << 10) + (hh << 6) + l4 * 4;
            #pragma unroll
            for (int ds = 0; ds < 4; ++ds) {
                uint2 o;
                o.x = pk2(acc[g][ds][0] * rl, acc[g][ds][1] * rl);
                o.y = pk2(acc[g][ds][2] * rl, acc[g][ds][3] * rl);
                *(uint2*)&y[rowbase + ds * 16] = o;
            }
        }
    }
}

extern "C" void kernel_launch(void* const* d_in, const int* in_sizes, int n_in,
                              void* d_out, int out_size, void* d_ws, size_t ws_size,
                              hipStream_t stream) {
    const float* x  = (const float*)d_in[0];
    const float* wq = (const float*)d_in[1];
    const float* wk = (const float*)d_in[2];
    const float* wv = (const float*)d_in[3];
    const float* wo = (const float*)d_in[4];
    float* out = (float*)d_out;

    const size_t M1 = 1u << 20;
    unsigned short* x16  = (unsigned short*)d_ws;          // 4M
    unsigned short* wq16 = x16 + 4 * M1;                   // 1M
    unsigned short* wk16 = wq16 + M1;
    unsigned short* wv16 = wk16 + M1;
    unsigned short* wot  = wv16 + M1;                      // 1M
    unsigned short* qbuf = wot + M1;                       // 4M [B,H,T,64]
    unsigned short* kbuf = qbuf + 4 * M1;                  // 4M
    unsigned short* vtb  = kbuf + 4 * M1;                  // 4M [1024][4096] sigma-perm
    unsigned short* ybuf = vtb + 4 * M1;                   // 4M [4096][1024]

    dim3 blk(256);
    prep<<<3840, blk, 0, stream>>>(x, wq, wk, wv, wo, x16, wq16, wk16, wv16, wot);
    proj<<<768, blk, 0, stream>>>(x16, wq16, wk16, wv16, qbuf, kbuf, vtb);
    attn<<<512, dim3(512), 0, stream>>>(qbuf, kbuf, vtb, ybuf);
    outp<<<256, blk, 0, stream>>>(ybuf, wot, out);
}

// Round 5
// 169.107 us; speedup vs baseline: 1.0662x; 1.0269x over previous
//
#include <hip/hip_runtime.h>

// B=2, T=2048, C=1024, H=16, DQK=DV=64. Inputs fp32, output fp32, bf16 MFMA inside.

typedef short bf16x4 __attribute__((ext_vector_type(4)));
typedef short bf16x8 __attribute__((ext_vector_type(8)));
typedef float f32x4 __attribute__((ext_vector_type(4)));

#define MFMA_BF16 __builtin_amdgcn_mfma_f32_16x16x32_bf16

// log2(e)/8: Q pre-scale so softmax runs in base-2 domain (exp2 = bare v_exp_f32)
#define QSCALE 0.18033688011112042f

__device__ __forceinline__ unsigned short f2bf(float f) {
    union { float f; unsigned u; } un; un.f = f;
    unsigned r = un.u + 0x7fffu + ((un.u >> 16) & 1u);  // RNE
    return (unsigned short)(r >> 16);
}
__device__ __forceinline__ unsigned pk2(float a, float b) {
    return (unsigned)f2bf(a) | ((unsigned)f2bf(b) << 16);
}
// truncating pack of two floats into packed bf16x2: one v_perm_b32 (R19)
__device__ __forceinline__ unsigned pk2t(float a, float b) {
    union { float f; unsigned u; } ua, ub; ua.f = a; ub.f = b;
    return __builtin_amdgcn_perm(ub.u, ua.u, 0x07060302u);
}
__device__ __forceinline__ void gload16(const void* g, void* l) {
    __builtin_amdgcn_global_load_lds(
        (const __attribute__((address_space(1))) unsigned int*)g,
        (__attribute__((address_space(3))) unsigned int*)l, 16, 0, 0);
}

// ---------- fused prep: x/wq/wk/wv fp32->bf16, wo fp32->bf16 transposed ----------
__global__ __launch_bounds__(256) void prep(
    const float* __restrict__ x, const float* __restrict__ wq,
    const float* __restrict__ wk, const float* __restrict__ wv,
    const float* __restrict__ wo,
    unsigned short* __restrict__ x16, unsigned short* __restrict__ wq16,
    unsigned short* __restrict__ wk16, unsigned short* __restrict__ wv16,
    unsigned short* __restrict__ wot)
{
    const int bid = blockIdx.x;
    if (bid < 3584) {
        const float* s; unsigned short* d; int off;
        if (bid < 2048)      { s = x;  d = x16;  off = bid * 2048; }
        else if (bid < 2560) { s = wq; d = wq16; off = (bid - 2048) * 2048; }
        else if (bid < 3072) { s = wk; d = wk16; off = (bid - 2560) * 2048; }
        else                 { s = wv; d = wv16; off = (bid - 3072) * 2048; }
        int i = off + threadIdx.x * 8;
        float4 f0 = *(const float4*)&s[i], f1 = *(const float4*)&s[i + 4];
        uint4 o;
        o.x = pk2(f0.x, f0.y); o.y = pk2(f0.z, f0.w);
        o.z = pk2(f1.x, f1.y); o.w = pk2(f1.z, f1.w);
        *(uint4*)&d[i] = o;
    } else {
        // wo [K=1024][N=1024] -> wot [N][K] bf16
        __shared__ unsigned short t[64 * 72];
        const int b2 = bid - 3584;
        const int k0 = (b2 & 15) << 6, n0 = (b2 >> 4) << 6;
        const int r = threadIdx.x >> 2, cg = (threadIdx.x & 3) << 4;
        const float* src = &wo[(k0 + r) * 1024 + n0 + cg];
        #pragma unroll
        for (int j = 0; j < 16; j += 4) {
            float4 f = *(const float4*)&src[j];
            t[(cg + j + 0) * 72 + r] = f2bf(f.x);
            t[(cg + j + 1) * 72 + r] = f2bf(f.y);
            t[(cg + j + 2) * 72 + r] = f2bf(f.z);
            t[(cg + j + 3) * 72 + r] = f2bf(f.w);
        }
        __syncthreads();
        unsigned short* dst = &wot[(n0 + r) * 1024 + k0 + cg];
        unsigned short* tr = &t[r * 72 + cg];
        unsigned v[16];
        #pragma unroll
        for (int j = 0; j < 16; ++j) v[j] = tr[j];
        uint4 o0, o1;
        o0.x = v[0] | (v[1] << 16);   o0.y = v[2] | (v[3] << 16);
        o0.z = v[4] | (v[5] << 16);   o0.w = v[6] | (v[7] << 16);
        o1.x = v[8] | (v[9] << 16);   o1.y = v[10] | (v[11] << 16);
        o1.z = v[12] | (v[13] << 16); o1.w = v[14] | (v[15] << 16);
        *(uint4*)&dst[0] = o0;
        *(uint4*)&dst[8] = o1;
    }
}

// ---------- 128x128 bf16 GEMM, K=1024: BK=32 dbuf gload16, fully unrolled ----------
// R16 data-side XOR bank swizzle (validated): G-chunk = (lane&3) ^ ((r16>>1)&3);
// readers use chunk l4 ^ ((l15>>1)&3). mode 2 = vtb store with sigma permutation.
__device__ __forceinline__ void gemm_body(
    const unsigned short* __restrict__ A, const unsigned short* __restrict__ Bm,
    void* __restrict__ C, int m0, int n0, int mode, int ldc, float sc)
{
    __shared__ unsigned short sa[2][128 * 32];
    __shared__ unsigned short sb[2][128 * 32];
    const int tid = threadIdx.x, wave = tid >> 6, lane = tid & 63;
    const int l15 = lane & 15, l4 = lane >> 4;
    const int wm = (wave >> 1) << 6, wn = (wave & 1) << 6;

    const int r16 = lane >> 2;                               // 0..15
    const int gcol = (((lane & 3) ^ ((r16 >> 1) & 3)) << 3); // swizzled 16B chunk
    const int rcol = (l4 ^ ((l15 >> 1) & 3)) << 3;           // read-side chunk
    const unsigned short* Ag0 = &A[(size_t)(m0 + wave * 16 + r16) * 1024 + gcol];
    const unsigned short* Ag1 = Ag0 + (size_t)64 * 1024;
    const unsigned short* Bg0 = &Bm[(size_t)(n0 + wave * 16 + r16) * 1024 + gcol];
    const unsigned short* Bg1 = Bg0 + (size_t)64 * 1024;
    const int lb0 = (wave * 16) * 32;      // wave-uniform LDS bases (elements)
    const int lb1 = (64 + wave * 16) * 32;

    gload16(Ag0, &sa[0][lb0]);
    gload16(Ag1, &sa[0][lb1]);
    gload16(Bg0, &sb[0][lb0]);
    gload16(Bg1, &sb[0][lb1]);
    __syncthreads();

    f32x4 acc[4][4] = {};

    #pragma unroll
    for (int kk = 0; kk < 32; ++kk) {
        const int cur = kk & 1;
        if (kk < 31) {
            const int off = (kk + 1) * 32;
            const int nxt = 1 - cur;
            gload16(Ag0 + off, &sa[nxt][lb0]);
            gload16(Ag1 + off, &sa[nxt][lb1]);
            gload16(Bg0 + off, &sb[nxt][lb0]);
            gload16(Bg1 + off, &sb[nxt][lb1]);
        }
        bf16x8 af[4], bf4[4];
        #pragma unroll
        for (int i = 0; i < 4; ++i)
            af[i] = *(const bf16x8*)&sa[cur][(wm + i * 16 + l15) * 32 + rcol];
        #pragma unroll
        for (int j = 0; j < 4; ++j)
            bf4[j] = *(const bf16x8*)&sb[cur][(wn + j * 16 + l15) * 32 + rcol];
        #pragma unroll
        for (int i = 0; i < 4; ++i)
            #pragma unroll
            for (int j = 0; j < 4; ++j)
                acc[i][j] = MFMA_BF16(af[i], bf4[j], acc[i][j], 0, 0, 0);
        __syncthreads();   // next-slab loads have flown during the MFMAs above
    }

    #pragma unroll
    for (int i = 0; i < 4; ++i)
        #pragma unroll
        for (int j = 0; j < 4; ++j)
            #pragma unroll
            for (int r = 0; r < 4; ++r) {
                int row = m0 + wm + i * 16 + l4 * 4 + r;
                int col = n0 + wn + j * 16 + l15;
                float val = acc[i][j][r];
                if (mode == 0) {
                    int nb = row >> 11, t = row & 2047;
                    int hh = col >> 6, dd = col & 63;
                    ((unsigned short*)C)[(((nb << 4) + hh) * 2048 + t) * 64 + dd] =
                        f2bf(val * sc);
                } else if (mode == 1) {
                    ((float*)C)[(size_t)row * ldc + col] = val;
                } else {
                    // sigma permutation within each 32-col block (see R15)
                    int s = col & 31;
                    int cp = (col & ~31) | (((s >> 2) & 3) << 3)
                                         | (((s >> 4) & 1) << 2) | (s & 3);
                    ((unsigned short*)C)[(size_t)row * ldc + cp] = f2bf(val);
                }
            }
}

// grid 768: [0,512) QK fused | [512,768) V^T = Wv @ X^T (sigma-permuted cols)
__global__ __launch_bounds__(256) void proj(
    const unsigned short* __restrict__ x16,
    const unsigned short* __restrict__ wq16,
    const unsigned short* __restrict__ wk16,
    const unsigned short* __restrict__ wv16,
    unsigned short* __restrict__ qbuf,
    unsigned short* __restrict__ kbuf,
    unsigned short* __restrict__ vtb)
{
    const int bid = blockIdx.x;
    if (bid < 512) {
        int m0 = (bid & 31) << 7;
        int n0g = (bid >> 5) << 7;
        if (n0g < 1024)
            gemm_body(x16, wq16, qbuf, m0, n0g, 0, 0, QSCALE);
        else
            gemm_body(x16, wk16, kbuf, m0, n0g - 1024, 0, 0, 1.0f);
    } else {
        int v = bid - 512;
        gemm_body(wv16, x16, vtb, (v & 7) << 7, (v >> 3) << 7, 2, 4096, 1.0f);
    }
}

// ---------- out = Y @ Wo^T: 128x128 gemm_body tiles, grid 256 (R17 best) ----------
__global__ __launch_bounds__(256) void outp(
    const unsigned short* __restrict__ ybuf,
    const unsigned short* __restrict__ wot,
    float* __restrict__ out)
{
    const int bid = blockIdx.x;
    gemm_body(ybuf, wot, out, (bid & 31) << 7, (bid >> 5) << 7, 1, 1024, 1.0f);
}

// ---------- flash causal attention: 64-row tiles, paired in-block, split-K (R21) ----------
// R20 post-mortem: WRITE_SIZE 8.2->27.5MB = per-thread scratch spills (state
// didn't fit the 128-reg/4-wave tier), and time-avg occupancy 25% = light
// partner blocks die instantly, heavy blocks run solo.
// R21: 64-row Q tiles (32 tiles). Block (pr,bh) processes tile 31-pr THEN
// tile pr sequentially: supersteps = ((31-pr)>>1+1)+((pr>>1)+1) = 17 for every
// block -> perfect balance, constant 2 blocks/CU, 4 waves/SIMD for the whole
// kernel. Halved per-wave state (qf 8, acc 16 AGPR, s_acc 16 AGPR, pe 16)
// fits the 4-wave reg tier with room -> no spill.
// Split-K parity kept (waves 0-3 even k-tiles, 4-7 odd; exact f32 LDS merge,
// same summation order as R20 -> identical numerics).
__global__ __launch_bounds__(512, 4) void attn(
    const unsigned short* __restrict__ q,
    const unsigned short* __restrict__ k,
    const unsigned short* __restrict__ vt,
    unsigned short* __restrict__ y)
{
    __shared__ unsigned short sk[2][2][64 * 64];   // [stage][parity][s][d]
    __shared__ unsigned short sv[2][2][64 * 64];   // [stage][parity][d][s-perm]
    const int tid = threadIdx.x, wave = tid >> 6, lane = tid & 63;
    const int ws = wave & 3, wk2 = wave >> 2;      // row-slice, k-parity
    const int l15 = lane & 15, l4 = lane >> 4;
    const int bid = blockIdx.x;
    const int pr = bid >> 5;                       // 0..15 (pair index)
    const int bh = bid & 31;
    const int nb = bh >> 4, hh = bh & 15;
    const size_t base = (size_t)bh << 17;

    // staging: 8 waves x 8 rows cover all 64 rows of a tile in ONE gload16 call
    const int lrow = lane >> 3;                           // 0..7 local row
    const int gch = ((lane & 7) ^ lrow) << 3;             // swizzled chunk (elems)
    const int row = wave * 8 + lrow;                      // 0..63
    const unsigned short* kg = &k[base + (size_t)row * 64 + gch];
    const unsigned short* vg = &vt[(size_t)((hh << 6) + row) * 4096 + (nb << 11) + gch];
    const int lb = (wave * 8) * 64;                       // wave-uniform LDS base

    // read-side swizzled chunk offset for kf/vf (elements)
    const int rch0 = ((0 + l4) ^ (l15 & 7)) << 3;   // ks=0
    const int rch1 = ((4 + l4) ^ (l15 & 7)) << 3;   // ks=1

    // merge scratch views over the (then-dead) staging buffers
    float* mrg = (float*)&sk[0][0][0];
    float* lsr = (float*)&sv[0][0][0];
    const int mslot = (ws << 6) + lane;             // 0..255
    const int mb = mslot << 4;                      // 16 floats/thread

    auto process = [&](const int t) {
        const int q0 = t << 6;
        // Q fragments (B-operand: n=l15 -> q row, k=l4*8..+7 -> d)
        bf16x8 qf[2];
        #pragma unroll
        for (int ks = 0; ks < 2; ++ks)
            qf[ks] = *(const bf16x8*)
                &q[base + (size_t)(q0 + ws * 16 + l15) * 64 + ks * 32 + l4 * 8];

        float l_sum = 0.f;
        f32x4 acc[4] = {};
        const int nsup = (t >> 1) + 1;              // supersteps for this tile

        auto stage_pair = [&](const int sbuf, const int p) {
            gload16(kg + ((size_t)p << 13), &sk[sbuf][0][lb]);   // k-tile 2p
            gload16(vg + (p << 7),          &sv[sbuf][0][lb]);
            if (2 * p + 1 <= t) {                                // k-tile 2p+1
                gload16(kg + ((size_t)p << 13) + 4096, &sk[sbuf][1][lb]);
                gload16(vg + (p << 7) + 64,            &sv[sbuf][1][lb]);
            }
        };

        stage_pair(0, 0);
        __syncthreads();

        // superstep body; LITERAL cur at call sites so LDS bases fold to imms
        auto sstep = [&](const int cur, const int p) {
            if (p + 1 < nsup) stage_pair(cur ^ 1, p + 1);
            const int st = 2 * p + wk2;
            if (st <= t) {                           // wave-uniform predicate
                const unsigned short* skc = &sk[cur][wk2][0];
                const unsigned short* svc = &sv[cur][wk2][0];

                f32x4 s_acc[4] = {};
                #pragma unroll
                for (int ns = 0; ns < 4; ++ns) {
                    bf16x8 kf0 = *(const bf16x8*)&skc[(ns * 16 + l15) * 64 + rch0];
                    bf16x8 kf1 = *(const bf16x8*)&skc[(ns * 16 + l15) * 64 + rch1];
                    s_acc[ns] = MFMA_BF16(kf0, qf[0], s_acc[ns], 0, 0, 0);
                    s_acc[ns] = MFMA_BF16(kf1, qf[1], s_acc[ns], 0, 0, 0);
                }

                // causal mask: only the diagonal k-tile (st == t) intersects
                if (st == t) {
                    const int ql = ws * 16 + l15;
                    #pragma unroll
                    for (int ns = 0; ns < 4; ++ns)
                        #pragma unroll
                        for (int r = 0; r < 4; ++r)
                            if (ns * 16 + l4 * 4 + r > ql) s_acc[ns][r] = -1e30f;
                }

                float pe[4][4];
                #pragma unroll
                for (int ns = 0; ns < 4; ++ns) {
                    #pragma unroll
                    for (int r = 0; r < 4; ++r) pe[ns][r] = exp2f(s_acc[ns][r]);
                    l_sum += (pe[ns][0] + pe[ns][1]) + (pe[ns][2] + pe[ns][3]);
                }

                #pragma unroll
                for (int ks = 0; ks < 2; ++ks) {
                    uint4 pw;
                    pw.x = pk2t(pe[2 * ks][0], pe[2 * ks][1]);
                    pw.y = pk2t(pe[2 * ks][2], pe[2 * ks][3]);
                    pw.z = pk2t(pe[2 * ks + 1][0], pe[2 * ks + 1][1]);
                    pw.w = pk2t(pe[2 * ks + 1][2], pe[2 * ks + 1][3]);
                    bf16x8 pf = *(bf16x8*)&pw;
                    const int rch = ks ? rch1 : rch0;
                    #pragma unroll
                    for (int ds = 0; ds < 4; ++ds) {
                        bf16x8 vf = *(const bf16x8*)&svc[(ds * 16 + l15) * 64 + rch];
                        acc[ds] = MFMA_BF16(vf, pf, acc[ds], 0, 0, 0);
                    }
                }
            }
            __syncthreads();   // next pair's gload16 deposits flew during compute
        };

        int p = 0;
        for (; p + 2 <= nsup; p += 2) { sstep(0, p); sstep(1, p + 1); }
        if (p < nsup) sstep(0, p);

        // ---- cross-parity merge through LDS (exact f32 adds) ----
        if (wk2 == 1) {
            #pragma unroll
            for (int ds = 0; ds < 4; ++ds)
                *(f32x4*)&mrg[mb + ((ds ^ (lane & 3)) << 2)] = acc[ds];
            lsr[mslot] = l_sum;
        }
        __syncthreads();
        if (wk2 == 0) {
            #pragma unroll
            for (int ds = 0; ds < 4; ++ds)
                acc[ds] += *(const f32x4*)&mrg[mb + ((ds ^ (lane & 3)) << 2)];
            l_sum += lsr[mslot];

            float ls = l_sum;
            ls += __shfl_xor(ls, 16);
            ls += __shfl_xor(ls, 32);
            const float rl = __builtin_amdgcn_rcpf(ls);

            const size_t rowbase =
                ((size_t)((nb << 11) + q0 + ws * 16 + l15) << 10) + (hh << 6) + l4 * 4;
            #pragma unroll
            for (int ds = 0; ds < 4; ++ds) {
                uint2 o;
                o.x = pk2(acc[ds][0] * rl, acc[ds][1] * rl);
                o.y = pk2(acc[ds][2] * rl, acc[ds][3] * rl);
                *(uint2*)&y[rowbase + ds * 16] = o;
            }
        }
        __syncthreads();   // merge reads done before next tile's staging reuses LDS
    };

    process(31 - pr);   // heavy tile first
    process(pr);        // complement: total supersteps = 17 for every block
}

extern "C" void kernel_launch(void* const* d_in, const int* in_sizes, int n_in,
                              void* d_out, int out_size, void* d_ws, size_t ws_size,
                              hipStream_t stream) {
    const float* x  = (const float*)d_in[0];
    const float* wq = (const float*)d_in[1];
    const float* wk = (const float*)d_in[2];
    const float* wv = (const float*)d_in[3];
    const float* wo = (const float*)d_in[4];
    float* out = (float*)d_out;

    const size_t M1 = 1u << 20;
    unsigned short* x16  = (unsigned short*)d_ws;          // 4M
    unsigned short* wq16 = x16 + 4 * M1;                   // 1M
    unsigned short* wk16 = wq16 + M1;
    unsigned short* wv16 = wk16 + M1;
    unsigned short* wot  = wv16 + M1;                      // 1M
    unsigned short* qbuf = wot + M1;                       // 4M [B,H,T,64]
    unsigned short* kbuf = qbuf + 4 * M1;                  // 4M
    unsigned short* vtb  = kbuf + 4 * M1;                  // 4M [1024][4096] sigma-perm
    unsigned short* ybuf = vtb + 4 * M1;                   // 4M [4096][1024]

    dim3 blk(256);
    prep<<<3840, blk, 0, stream>>>(x, wq, wk, wv, wo, x16, wq16, wk16, wv16, wot);
    proj<<<768, blk, 0, stream>>>(x16, wq16, wk16, wv16, qbuf, kbuf, vtb);
    attn<<<512, dim3(512), 0, stream>>>(qbuf, kbuf, vtb, ybuf);
    outp<<<256, blk, 0, stream>>>(ybuf, wot, out);
}